// Round 17
// baseline (115.140 us; speedup 1.0000x reference)
//
#include <hip/hip_runtime.h>

typedef __bf16 bf16;
typedef bf16 bf16x8 __attribute__((ext_vector_type(8)));
typedef float f32x4 __attribute__((ext_vector_type(4)));
typedef unsigned short u16;
typedef u16 u16x4 __attribute__((ext_vector_type(4)));
typedef u16 u16x8 __attribute__((ext_vector_type(8)));

typedef const __attribute__((address_space(1))) void* gptr_t;
typedef __attribute__((address_space(3))) void* sptr_t;

__device__ __forceinline__ void async16(const void* g, void* l) {
  __builtin_amdgcn_global_load_lds((gptr_t)g, (sptr_t)l, 16, 0, 0);
}
__device__ __forceinline__ u16 f2bf(float v) {
  return __builtin_bit_cast(u16, (bf16)v);
}

// Fragment-packed layout (u16 elems): for matrix [R][K], element (r,k) lives at
//   ((r>>4)*(K/32) + (k>>5))*512 + ((k>>3)&3)*128 + (r&15)*8 + (k&7)
__device__ __forceinline__ size_t paddr(int r, int k, int KT) {
  return (size_t)((r >> 4) * KT + (k >> 5)) * 512 + ((k >> 3) & 3) * 128 +
         (r & 15) * 8 + (k & 7);
}

// ------- prep: src pack->packed A (blocks 0..4095) + W trans->packed B ------
__global__ void kPrep(const float* __restrict__ src, u16* __restrict__ Xp,
                      const float* __restrict__ Wq, const float* __restrict__ Wk,
                      const float* __restrict__ Wv, const float* __restrict__ Wo,
                      u16* __restrict__ Wp) {
  __shared__ float tile[32][33];
  const int bid = blockIdx.x, tid = threadIdx.x;
  if (bid < 4096) {
    const int i = (bid * 256 + tid) * 4;
    const int m = i >> 10, k = i & 1023;
    float4 v = *(const float4*)&src[i];
    u16x4 o = {f2bf(v.x), f2bf(v.y), f2bf(v.z), f2bf(v.w)};
    *(u16x4*)&Xp[paddr(m, k, 32)] = o;
  } else {
    const int t = bid - 4096;
    const int z = t >> 10, tt = t & 1023;
    const float* W = (z == 0) ? Wq : (z == 1) ? Wk : (z == 2) ? Wv : Wo;
    const int n0 = (tt & 31) * 32, k0 = (tt >> 5) * 32;
    const int tx = tid & 31, ty = tid >> 5;
#pragma unroll
    for (int j = 0; j < 4; ++j)
      tile[ty + j * 8][tx] = W[(size_t)(k0 + ty + j * 8) * 1024 + n0 + tx];
    __syncthreads();
    if (tid < 128) {
      const int sub = tid >> 6, l = tid & 63, hi = l >> 4, lo = l & 15;
      u16x8 o;
#pragma unroll
      for (int e = 0; e < 8; ++e) o[e] = f2bf(tile[hi * 8 + e][sub * 16 + lo]);
      const size_t ad = (size_t)z * 1048576 +
                        (size_t)(((n0 >> 4) + sub) * 32 + (k0 >> 5)) * 512 +
                        hi * 128 + lo * 8;
      *(u16x8*)&Wp[ad] = o;
    }
  }
}

// ---- QKV GEMM: HYBRID (r15 best). A-frags via LDS (linear async16 from
// packed layout, conflict-free ds_read), B-frags direct global->reg.
__global__ __launch_bounds__(256, 3) void kGemmQKV(
    const u16* __restrict__ A, const u16* __restrict__ Bt,
    const float* __restrict__ b0, const float* __restrict__ b1,
    const float* __restrict__ b2, u16* __restrict__ outQ) {
  __shared__ __align__(16) u16 Als[2][8 * 512];  // 8 A-frags (8 KB) x dbuf
  const int tid = threadIdx.x, l = tid & 63, w = tid >> 6;
  const int bid = (blockIdx.x & 7) * 96 + (blockIdx.x >> 3);  // XCD swizzle
  const int mb = bid & 31, nb = bid >> 5;
  const int mbase = mb * 128, nbase = nb * 128;
  const int wr = (w >> 1) * 64, wc = (w & 1) * 64;
  const int hi = l >> 4, lo = l & 15;

  const u16* bb[4];
#pragma unroll
  for (int nf = 0; nf < 4; ++nf)
    bb[nf] = &Bt[(size_t)((nbase + wc + nf * 16) >> 4) * 16384 + l * 8];

  f32x4 acc[4][4];
#pragma unroll
  for (int i = 0; i < 4; ++i)
#pragma unroll
    for (int j = 0; j < 4; ++j) acc[i][j] = (f32x4){0.f, 0.f, 0.f, 0.f};

  auto stageA = [&](int bufi, int kt) {  // 2 async16/wave, linear dest
#pragma unroll
    for (int i = 0; i < 2; ++i) {
      const int fr = w * 2 + i;
      async16(&A[(size_t)((mb * 8 + fr) * 32 + kt) * 512 + l * 8],
              &Als[bufi][fr * 512]);
    }
  };

  bf16x8 breg[2][4];
  stageA(0, 0);
#pragma unroll
  for (int nf = 0; nf < 4; ++nf) breg[0][nf] = *(const bf16x8*)&bb[nf][0];

  auto step = [&](int kt, bf16x8 (&bc)[4], bf16x8 (&bn)[4]) {
    const int cur = kt & 1;
    if (kt < 31) {
      stageA(cur ^ 1, kt + 1);
#pragma unroll
      for (int nf = 0; nf < 4; ++nf)
        bn[nf] = *(const bf16x8*)&bb[nf][(kt + 1) * 512];
      asm volatile("s_waitcnt vmcnt(6)" ::: "memory");  // A(kt) staged
    } else {
      asm volatile("s_waitcnt vmcnt(0)" ::: "memory");
    }
    __builtin_amdgcn_s_barrier();
    __builtin_amdgcn_sched_barrier(0);

    bf16x8 a[4];
#pragma unroll
    for (int mf = 0; mf < 4; ++mf)
      a[mf] = *(const bf16x8*)&Als[cur][((w >> 1) * 4 + mf) * 512 + l * 8];
#pragma unroll
    for (int mf = 0; mf < 4; ++mf)
#pragma unroll
      for (int nf = 0; nf < 4; ++nf)
        acc[mf][nf] = __builtin_amdgcn_mfma_f32_16x16x32_bf16(a[mf], bc[nf],
                                                              acc[mf][nf], 0, 0, 0);
    __builtin_amdgcn_s_barrier();
  };

  for (int kt2 = 0; kt2 < 32; kt2 += 2) {
    step(kt2, breg[0], breg[1]);
    step(kt2 + 1, breg[1], breg[0]);
  }

  u16* Qo = outQ;
  u16* Ko = outQ + 4 * 1048576;
  u16* Vo = outQ + 8 * 1048576;
  const int mat = nb >> 3;
  const float* bias = (mat == 0) ? b0 : (mat == 1) ? b1 : b2;
  const float qs = (mat == 0) ? 0.1803368801f : 1.0f;  // 1/8 * log2(e)
#pragma unroll
  for (int nf = 0; nf < 4; ++nf) {
    const int n = nbase + wc + nf * 16 + lo;
    const int cc = n & 1023, h = cc >> 6, d = cc & 63;
    const float bsv = bias[cc];
#pragma unroll
    for (int mf = 0; mf < 4; ++mf)
#pragma unroll
      for (int r = 0; r < 4; ++r) {
        const int m = mbase + wr + mf * 16 + hi * 4 + r;
        const int bb_ = m >> 11, t = m & 2047;
        const u16 hv = f2bf((acc[mf][nf][r] + bsv) * qs);
        const size_t hd = (size_t)(bb_ * 16 + h) * 131072;
        if (mat < 2) {  // Q/K packed over (t,d), KT=2
          (mat == 0 ? Qo : Ko)[hd + paddr(t, d, 2)] = hv;
        } else {  // V packed over (d,t), KT=64
          Vo[hd + paddr(d, t, 64)] = hv;
        }
      }
  }
}

// ---- out-proj GEMM: HYBRID (r15 best), 128x64 tile (grid 512). -------------
__global__ __launch_bounds__(256, 2) void kGemmO(
    const u16* __restrict__ A, const u16* __restrict__ Bt,
    const float* __restrict__ b0, float* __restrict__ outF) {
  __shared__ __align__(16) u16 Als[2][8 * 512];
  const int tid = threadIdx.x, l = tid & 63, w = tid >> 6;
  const int bid = (blockIdx.x & 7) * 64 + (blockIdx.x >> 3);  // XCD swizzle
  const int mb = bid & 31, nb = bid >> 5;
  const int mbase = mb * 128, nbase = nb * 64;
  const int wr = (w >> 1) * 64, wc = (w & 1) * 32;
  const int hi = l >> 4, lo = l & 15;

  const u16* bb[2];
#pragma unroll
  for (int nf = 0; nf < 2; ++nf)
    bb[nf] = &Bt[(size_t)((nbase + wc + nf * 16) >> 4) * 16384 + l * 8];

  f32x4 acc[4][2];
#pragma unroll
  for (int i = 0; i < 4; ++i)
#pragma unroll
    for (int j = 0; j < 2; ++j) acc[i][j] = (f32x4){0.f, 0.f, 0.f, 0.f};

  auto stageA = [&](int bufi, int kt) {
#pragma unroll
    for (int i = 0; i < 2; ++i) {
      const int fr = w * 2 + i;
      async16(&A[(size_t)((mb * 8 + fr) * 32 + kt) * 512 + l * 8],
              &Als[bufi][fr * 512]);
    }
  };

  bf16x8 breg[2][2];
  stageA(0, 0);
#pragma unroll
  for (int nf = 0; nf < 2; ++nf) breg[0][nf] = *(const bf16x8*)&bb[nf][0];

  auto step = [&](int kt, bf16x8 (&bc)[2], bf16x8 (&bn)[2]) {
    const int cur = kt & 1;
    if (kt < 31) {
      stageA(cur ^ 1, kt + 1);
#pragma unroll
      for (int nf = 0; nf < 2; ++nf)
        bn[nf] = *(const bf16x8*)&bb[nf][(kt + 1) * 512];
      asm volatile("s_waitcnt vmcnt(4)" ::: "memory");
    } else {
      asm volatile("s_waitcnt vmcnt(0)" ::: "memory");
    }
    __builtin_amdgcn_s_barrier();
    __builtin_amdgcn_sched_barrier(0);

    bf16x8 a[4];
#pragma unroll
    for (int mf = 0; mf < 4; ++mf)
      a[mf] = *(const bf16x8*)&Als[cur][((w >> 1) * 4 + mf) * 512 + l * 8];
#pragma unroll
    for (int mf = 0; mf < 4; ++mf)
#pragma unroll
      for (int nf = 0; nf < 2; ++nf)
        acc[mf][nf] = __builtin_amdgcn_mfma_f32_16x16x32_bf16(a[mf], bc[nf],
                                                              acc[mf][nf], 0, 0, 0);
    __builtin_amdgcn_s_barrier();
  };

  for (int kt2 = 0; kt2 < 32; kt2 += 2) {
    step(kt2, breg[0], breg[1]);
    step(kt2 + 1, breg[1], breg[0]);
  }

#pragma unroll
  for (int nf = 0; nf < 2; ++nf) {
    const int n = nbase + wc + nf * 16 + lo;
    const float bsv = b0[n];
#pragma unroll
    for (int mf = 0; mf < 4; ++mf)
#pragma unroll
      for (int r = 0; r < 4; ++r) {
        const int m = mbase + wr + mf * 16 + hi * 4 + r;
        outF[(size_t)m * 1024 + n] = acc[mf][nf][r] + bsv;
      }
  }
}

// -------- flash attention: QUAD q-tiles + XCD-resident KV (r15) + LDS-DMA
// staged K/V: 16 async16/block/step (8 K + 8 V frags, one per wave) replace
// 4x-redundant per-wave L1 reads (64KB -> 16KB TA traffic per step). K(st)
// frags are CONTIGUOUS in the packed layout ((st*8+f)*512); V slots linear.
// Double-buffered, staged one step ahead; one vmcnt(0)+barrier per step.
#define PSTR 36
__global__ __launch_bounds__(512, 2) void kAttn(const u16* __restrict__ Qp,
                                                const u16* __restrict__ Kp,
                                                const u16* __restrict__ Vp,
                                                u16* __restrict__ AOp) {
  __shared__ __align__(16) u16 Ksh[2][8 * 512];      // K(st) frags (8 KB) x2
  __shared__ __align__(16) u16 Vsh[2][8 * 512];      // V(st) frags (8 KB) x2
  __shared__ __align__(16) u16 Pl[8][16 * PSTR];     // per-wave P (9 KB)
  __shared__ __align__(16) float Red[4][2][16][64];  // odd-half O partials
  __shared__ float RedL[4][2][64];                   // odd-half denom partials
  const int tid = threadIdx.x, l = tid & 63, w = tid >> 6;  // w in [0,8)
  const int grp = w >> 1, half = w & 1;
  const int g = l >> 4, c = l & 15;
  const int id = blockIdx.x;  // 256 blocks
  const int xcd = id & 7, rem = id >> 3;
  const int pi = rem & 7, bh = (rem >> 3) * 8 + xcd;  // bh%8 == xcd
  const int qt0 = 31 - pi, qt1 = 16 + pi, qt2 = 15 - pi, qt3 = pi;
  const size_t head = (size_t)bh * 131072;
  const u16* Kh = Kp + head;
  const u16* Vh = Vp + head;

  bf16x8 aq0[2], aq1[2], aq2[2], aq3[2];
#pragma unroll
  for (int ks = 0; ks < 2; ++ks) {
    aq0[ks] = *(const bf16x8*)&Qp[head + (size_t)((qt0 * 4 + grp) * 2 + ks) * 512 + l * 8];
    aq1[ks] = *(const bf16x8*)&Qp[head + (size_t)((qt1 * 4 + grp) * 2 + ks) * 512 + l * 8];
    aq2[ks] = *(const bf16x8*)&Qp[head + (size_t)((qt2 * 4 + grp) * 2 + ks) * 512 + l * 8];
    aq3[ks] = *(const bf16x8*)&Qp[head + (size_t)((qt3 * 4 + grp) * 2 + ks) * 512 + l * 8];
  }

  f32x4 acc0[4], acc1[4], acc2[4], acc3[4];
#pragma unroll
  for (int i = 0; i < 4; ++i) {
    acc0[i] = (f32x4){0.f, 0.f, 0.f, 0.f};
    acc1[i] = (f32x4){0.f, 0.f, 0.f, 0.f};
    acc2[i] = (f32x4){0.f, 0.f, 0.f, 0.f};
    acc3[i] = (f32x4){0.f, 0.f, 0.f, 0.f};
  }
  float l0 = 0.f, l1 = 0.f, l2 = 0.f, l3 = 0.f;

  // Each wave stages ONE K frag (f=w: addr (st*8+w)*512, contiguous) and
  // ONE V slot (w=(nd<<1)|hh: addr (nd*64 + st*2 + hh)*512) per step.
  auto stageKV = [&](int buf, int st) {
    async16(&Kh[(size_t)(st * 8 + w) * 512 + l * 8], &Ksh[buf][w * 512]);
    async16(&Vh[(size_t)((w >> 1) * 64 + st * 2 + (w & 1)) * 512 + l * 8],
            &Vsh[buf][w * 512]);
  };

  bf16x8 kr[4], vr[4];

  auto qkTile = [&](const bf16x8* aq, f32x4* sT) {
#pragma unroll
    for (int sf = 0; sf < 2; ++sf)
#pragma unroll
      for (int ks = 0; ks < 2; ++ks)
        sT[sf] = __builtin_amdgcn_mfma_f32_16x16x32_bf16(kr[sf * 2 + ks], aq[ks],
                                                         sT[sf], 0, 0, 0);
  };

  auto finishTile = [&](const f32x4* sT, bool diag, f32x4* accO, float& lpart) {
    float v[8];
#pragma unroll
    for (int sf = 0; sf < 2; ++sf)
#pragma unroll
      for (int r = 0; r < 4; ++r) v[sf * 4 + r] = sT[sf][r];
    if (diag) {
      const int qin = grp * 16 + c;
#pragma unroll
      for (int sf = 0; sf < 2; ++sf)
#pragma unroll
        for (int r = 0; r < 4; ++r)
          if (half * 32 + sf * 16 + g * 4 + r > qin) v[sf * 4 + r] = -__builtin_inff();
    }
    float p[8];
#pragma unroll
    for (int i = 0; i < 8; ++i) p[i] = __builtin_exp2f(v[i]);  // exp2(-inf)=0
#pragma unroll
    for (int sf = 0; sf < 2; ++sf) {
      u16x4 q4 = {f2bf(p[sf * 4 + 0]), f2bf(p[sf * 4 + 1]),
                  f2bf(p[sf * 4 + 2]), f2bf(p[sf * 4 + 3])};
      *(u16x4*)&Pl[w][c * PSTR + sf * 16 + g * 4] = q4;
    }
    lpart += ((p[0] + p[1]) + (p[2] + p[3])) + ((p[4] + p[5]) + (p[6] + p[7]));
    bf16x8 pf = *(const bf16x8*)&Pl[w][c * PSTR + g * 8];
#pragma unroll
    for (int nd = 0; nd < 4; ++nd)
      accO[nd] = __builtin_amdgcn_mfma_f32_16x16x32_bf16(pf, vr[nd], accO[nd], 0, 0, 0);
  };

  stageKV(0, 0);
  asm volatile("s_waitcnt vmcnt(0)" ::: "memory");
  __builtin_amdgcn_s_barrier();

  const int nst = qt0 + 1;
  for (int st = 0; st < nst; ++st) {
    const int cur = st & 1;
    if (st + 1 < nst) stageKV(cur ^ 1, st + 1);  // hidden under compute

    // wave's frags from LDS (linear, conflict-free)
#pragma unroll
    for (int sf = 0; sf < 2; ++sf)
#pragma unroll
      for (int ks = 0; ks < 2; ++ks)
        kr[sf * 2 + ks] =
            *(const bf16x8*)&Ksh[cur][(half * 4 + sf * 2 + ks) * 512 + l * 8];
#pragma unroll
    for (int nd = 0; nd < 4; ++nd)
      vr[nd] = *(const bf16x8*)&Vsh[cur][(nd * 2 + half) * 512 + l * 8];

    f32x4 sT[2];
    if (st <= qt3) {
#pragma unroll
      for (int i = 0; i < 2; ++i) sT[i] = (f32x4){0.f, 0.f, 0.f, 0.f};
      qkTile(aq3, sT);
      finishTile(sT, st == qt3, acc3, l3);
    }
    if (st <= qt2) {
#pragma unroll
      for (int i = 0; i < 2; ++i) sT[i] = (f32x4){0.f, 0.f, 0.f, 0.f};
      qkTile(aq2, sT);
      finishTile(sT, st == qt2, acc2, l2);
    }
    if (st <= qt1) {
#pragma unroll
      for (int i = 0; i < 2; ++i) sT[i] = (f32x4){0.f, 0.f, 0.f, 0.f};
      qkTile(aq1, sT);
      finishTile(sT, st == qt1, acc1, l1);
    }
    {
#pragma unroll
      for (int i = 0; i < 2; ++i) sT[i] = (f32x4){0.f, 0.f, 0.f, 0.f};
      qkTile(aq0, sT);
      finishTile(sT, st == qt0, acc0, l0);
    }

    // next-step DMA (issued at top, ~full step ago) must land; then fence
    asm volatile("s_waitcnt vmcnt(0)" ::: "memory");
    __builtin_amdgcn_s_barrier();
    __builtin_amdgcn_sched_barrier(0);
  }

  const int b = bh >> 4, h = bh & 15;
  auto writeOut = [&](int qt, const f32x4* accO, float lc) {
#pragma unroll
    for (int r = 0; r < 4; ++r) {
      const float lr = __shfl(lc, g * 4 + r);
      const float rin = 1.0f / lr;
      const int mg = b * 2048 + qt * 64 + grp * 16 + g * 4 + r;
#pragma unroll
      for (int nd = 0; nd < 4; ++nd) {
        const int col = h * 64 + nd * 16 + c;
        AOp[paddr(mg, col, 32)] = f2bf(accO[nd][r] * rin);  // packed for GEMM-O
      }
    }
  };
  auto combinePair = [&](f32x4* accX, float lX, int qtX, f32x4* accY, float lY,
                         int qtY) {
    float lcX = lX + __shfl_xor(lX, 16);
    lcX += __shfl_xor(lcX, 32);
    float lcY = lY + __shfl_xor(lY, 16);
    lcY += __shfl_xor(lcY, 32);
    __syncthreads();
    if (half) {
#pragma unroll
      for (int nd = 0; nd < 4; ++nd)
#pragma unroll
        for (int r = 0; r < 4; ++r) {
          Red[grp][0][nd * 4 + r][l] = accX[nd][r];
          Red[grp][1][nd * 4 + r][l] = accY[nd][r];
        }
      RedL[grp][0][l] = lcX;
      RedL[grp][1][l] = lcY;
    }
    __syncthreads();
    if (!half) {
#pragma unroll
      for (int nd = 0; nd < 4; ++nd)
#pragma unroll
        for (int r = 0; r < 4; ++r) {
          accX[nd][r] += Red[grp][0][nd * 4 + r][l];
          accY[nd][r] += Red[grp][1][nd * 4 + r][l];
        }
      writeOut(qtX, accX, lcX + RedL[grp][0][l]);
      writeOut(qtY, accY, lcY + RedL[grp][1][l]);
    }
  };
  combinePair(acc0, l0, qt0, acc1, l1, qt1);
  combinePair(acc2, l2, qt2, acc3, l3, qt3);
}

extern "C" void kernel_launch(void* const* d_in, const int* in_sizes, int n_in,
                              void* d_out, int out_size, void* d_ws, size_t ws_size,
                              hipStream_t stream) {
  const float* src = (const float*)d_in[0];
  const float* Wq = (const float*)d_in[2];
  const float* bq = (const float*)d_in[3];
  const float* Wk = (const float*)d_in[4];
  const float* bk = (const float*)d_in[5];
  const float* Wv = (const float*)d_in[6];
  const float* bv = (const float*)d_in[7];
  const float* Wo = (const float*)d_in[8];
  const float* bo = (const float*)d_in[9];
  float* out = (float*)d_out;

  char* ws = (char*)d_ws;
  u16* Wp = (u16*)(ws);                           // [4][1024][1024] bf16 packed
  u16* Xp = (u16*)(ws + 8ull * 1024 * 1024);      // [4096][1024] bf16 packed
  u16* Qb = (u16*)(ws + 16ull * 1024 * 1024);     // Qp,Kp,Vp packed
  u16* AOp = (u16*)(ws + 40ull * 1024 * 1024);    // [4096][1024] bf16 packed

  kPrep<<<dim3(8192), dim3(256), 0, stream>>>(src, Xp, Wq, Wk, Wv, Wo, Wp);
  kGemmQKV<<<dim3(768), dim3(256), 0, stream>>>(Xp, Wp, bq, bk, bv, Qb);
  kAttn<<<dim3(256), dim3(512), 0, stream>>>(Qb, Qb + 4 * 1048576,
                                             Qb + 8 * 1048576, AOp);
  kGemmO<<<dim3(512), dim3(256), 0, stream>>>(AOp, Wp + 3ull * 1048576, bo, out);
}

// Round 18
// 103.526 us; speedup vs baseline: 1.1122x; 1.1122x over previous
//
#include <hip/hip_runtime.h>

typedef __bf16 bf16;
typedef bf16 bf16x8 __attribute__((ext_vector_type(8)));
typedef float f32x4 __attribute__((ext_vector_type(4)));
typedef unsigned short u16;
typedef u16 u16x4 __attribute__((ext_vector_type(4)));
typedef u16 u16x8 __attribute__((ext_vector_type(8)));

typedef const __attribute__((address_space(1))) void* gptr_t;
typedef __attribute__((address_space(3))) void* sptr_t;

__device__ __forceinline__ void async16(const void* g, void* l) {
  __builtin_amdgcn_global_load_lds((gptr_t)g, (sptr_t)l, 16, 0, 0);
}
__device__ __forceinline__ u16 f2bf(float v) {
  return __builtin_bit_cast(u16, (bf16)v);
}

// Fragment-packed layout (u16 elems): for matrix [R][K], element (r,k) lives at
//   ((r>>4)*(K/32) + (k>>5))*512 + ((k>>3)&3)*128 + (r&15)*8 + (k&7)
__device__ __forceinline__ size_t paddr(int r, int k, int KT) {
  return (size_t)((r >> 4) * KT + (k >> 5)) * 512 + ((k >> 3) & 3) * 128 +
         (r & 15) * 8 + (k & 7);
}

// ------- prep: src pack->packed A (blocks 0..4095) + W trans->packed B ------
__global__ void kPrep(const float* __restrict__ src, u16* __restrict__ Xp,
                      const float* __restrict__ Wq, const float* __restrict__ Wk,
                      const float* __restrict__ Wv, const float* __restrict__ Wo,
                      u16* __restrict__ Wp) {
  __shared__ float tile[32][33];
  const int bid = blockIdx.x, tid = threadIdx.x;
  if (bid < 4096) {
    const int i = (bid * 256 + tid) * 4;
    const int m = i >> 10, k = i & 1023;
    float4 v = *(const float4*)&src[i];
    u16x4 o = {f2bf(v.x), f2bf(v.y), f2bf(v.z), f2bf(v.w)};
    *(u16x4*)&Xp[paddr(m, k, 32)] = o;
  } else {
    const int t = bid - 4096;
    const int z = t >> 10, tt = t & 1023;
    const float* W = (z == 0) ? Wq : (z == 1) ? Wk : (z == 2) ? Wv : Wo;
    const int n0 = (tt & 31) * 32, k0 = (tt >> 5) * 32;
    const int tx = tid & 31, ty = tid >> 5;
#pragma unroll
    for (int j = 0; j < 4; ++j)
      tile[ty + j * 8][tx] = W[(size_t)(k0 + ty + j * 8) * 1024 + n0 + tx];
    __syncthreads();
    if (tid < 128) {
      const int sub = tid >> 6, l = tid & 63, hi = l >> 4, lo = l & 15;
      u16x8 o;
#pragma unroll
      for (int e = 0; e < 8; ++e) o[e] = f2bf(tile[hi * 8 + e][sub * 16 + lo]);
      const size_t ad = (size_t)z * 1048576 +
                        (size_t)(((n0 >> 4) + sub) * 32 + (k0 >> 5)) * 512 +
                        hi * 128 + lo * 8;
      *(u16x8*)&Wp[ad] = o;
    }
  }
}

// ---- QKV GEMM: HYBRID (r15 best). A-frags via LDS (linear async16 from
// packed layout, conflict-free ds_read), B-frags direct global->reg.
__global__ __launch_bounds__(256, 3) void kGemmQKV(
    const u16* __restrict__ A, const u16* __restrict__ Bt,
    const float* __restrict__ b0, const float* __restrict__ b1,
    const float* __restrict__ b2, u16* __restrict__ outQ) {
  __shared__ __align__(16) u16 Als[2][8 * 512];  // 8 A-frags (8 KB) x dbuf
  const int tid = threadIdx.x, l = tid & 63, w = tid >> 6;
  const int bid = (blockIdx.x & 7) * 96 + (blockIdx.x >> 3);  // XCD swizzle
  const int mb = bid & 31, nb = bid >> 5;
  const int mbase = mb * 128, nbase = nb * 128;
  const int wr = (w >> 1) * 64, wc = (w & 1) * 64;
  const int hi = l >> 4, lo = l & 15;

  const u16* bb[4];
#pragma unroll
  for (int nf = 0; nf < 4; ++nf)
    bb[nf] = &Bt[(size_t)((nbase + wc + nf * 16) >> 4) * 16384 + l * 8];

  f32x4 acc[4][4];
#pragma unroll
  for (int i = 0; i < 4; ++i)
#pragma unroll
    for (int j = 0; j < 4; ++j) acc[i][j] = (f32x4){0.f, 0.f, 0.f, 0.f};

  auto stageA = [&](int bufi, int kt) {  // 2 async16/wave, linear dest
#pragma unroll
    for (int i = 0; i < 2; ++i) {
      const int fr = w * 2 + i;
      async16(&A[(size_t)((mb * 8 + fr) * 32 + kt) * 512 + l * 8],
              &Als[bufi][fr * 512]);
    }
  };

  bf16x8 breg[2][4];
  stageA(0, 0);
#pragma unroll
  for (int nf = 0; nf < 4; ++nf) breg[0][nf] = *(const bf16x8*)&bb[nf][0];

  auto step = [&](int kt, bf16x8 (&bc)[4], bf16x8 (&bn)[4]) {
    const int cur = kt & 1;
    if (kt < 31) {
      stageA(cur ^ 1, kt + 1);
#pragma unroll
      for (int nf = 0; nf < 4; ++nf)
        bn[nf] = *(const bf16x8*)&bb[nf][(kt + 1) * 512];
      asm volatile("s_waitcnt vmcnt(6)" ::: "memory");  // A(kt) staged
    } else {
      asm volatile("s_waitcnt vmcnt(0)" ::: "memory");
    }
    __builtin_amdgcn_s_barrier();
    __builtin_amdgcn_sched_barrier(0);

    bf16x8 a[4];
#pragma unroll
    for (int mf = 0; mf < 4; ++mf)
      a[mf] = *(const bf16x8*)&Als[cur][((w >> 1) * 4 + mf) * 512 + l * 8];
#pragma unroll
    for (int mf = 0; mf < 4; ++mf)
#pragma unroll
      for (int nf = 0; nf < 4; ++nf)
        acc[mf][nf] = __builtin_amdgcn_mfma_f32_16x16x32_bf16(a[mf], bc[nf],
                                                              acc[mf][nf], 0, 0, 0);
    __builtin_amdgcn_s_barrier();
  };

  for (int kt2 = 0; kt2 < 32; kt2 += 2) {
    step(kt2, breg[0], breg[1]);
    step(kt2 + 1, breg[1], breg[0]);
  }

  u16* Qo = outQ;
  u16* Ko = outQ + 4 * 1048576;
  u16* Vo = outQ + 8 * 1048576;
  const int mat = nb >> 3;
  const float* bias = (mat == 0) ? b0 : (mat == 1) ? b1 : b2;
  const float qs = (mat == 0) ? 0.1803368801f : 1.0f;  // 1/8 * log2(e)
#pragma unroll
  for (int nf = 0; nf < 4; ++nf) {
    const int n = nbase + wc + nf * 16 + lo;
    const int cc = n & 1023, h = cc >> 6, d = cc & 63;
    const float bsv = bias[cc];
#pragma unroll
    for (int mf = 0; mf < 4; ++mf)
#pragma unroll
      for (int r = 0; r < 4; ++r) {
        const int m = mbase + wr + mf * 16 + hi * 4 + r;
        const int bb_ = m >> 11, t = m & 2047;
        const u16 hv = f2bf((acc[mf][nf][r] + bsv) * qs);
        const size_t hd = (size_t)(bb_ * 16 + h) * 131072;
        if (mat < 2) {  // Q/K packed over (t,d), KT=2
          (mat == 0 ? Qo : Ko)[hd + paddr(t, d, 2)] = hv;
        } else {  // V packed over (d,t), KT=64
          Vo[hd + paddr(d, t, 64)] = hv;
        }
      }
  }
}

// ---- out-proj GEMM: HYBRID (r15 best), 128x64 tile (grid 512). -------------
__global__ __launch_bounds__(256, 2) void kGemmO(
    const u16* __restrict__ A, const u16* __restrict__ Bt,
    const float* __restrict__ b0, float* __restrict__ outF) {
  __shared__ __align__(16) u16 Als[2][8 * 512];
  const int tid = threadIdx.x, l = tid & 63, w = tid >> 6;
  const int bid = (blockIdx.x & 7) * 64 + (blockIdx.x >> 3);  // XCD swizzle
  const int mb = bid & 31, nb = bid >> 5;
  const int mbase = mb * 128, nbase = nb * 64;
  const int wr = (w >> 1) * 64, wc = (w & 1) * 32;
  const int hi = l >> 4, lo = l & 15;

  const u16* bb[2];
#pragma unroll
  for (int nf = 0; nf < 2; ++nf)
    bb[nf] = &Bt[(size_t)((nbase + wc + nf * 16) >> 4) * 16384 + l * 8];

  f32x4 acc[4][2];
#pragma unroll
  for (int i = 0; i < 4; ++i)
#pragma unroll
    for (int j = 0; j < 2; ++j) acc[i][j] = (f32x4){0.f, 0.f, 0.f, 0.f};

  auto stageA = [&](int bufi, int kt) {
#pragma unroll
    for (int i = 0; i < 2; ++i) {
      const int fr = w * 2 + i;
      async16(&A[(size_t)((mb * 8 + fr) * 32 + kt) * 512 + l * 8],
              &Als[bufi][fr * 512]);
    }
  };

  bf16x8 breg[2][2];
  stageA(0, 0);
#pragma unroll
  for (int nf = 0; nf < 2; ++nf) breg[0][nf] = *(const bf16x8*)&bb[nf][0];

  auto step = [&](int kt, bf16x8 (&bc)[2], bf16x8 (&bn)[2]) {
    const int cur = kt & 1;
    if (kt < 31) {
      stageA(cur ^ 1, kt + 1);
#pragma unroll
      for (int nf = 0; nf < 2; ++nf)
        bn[nf] = *(const bf16x8*)&bb[nf][(kt + 1) * 512];
      asm volatile("s_waitcnt vmcnt(4)" ::: "memory");
    } else {
      asm volatile("s_waitcnt vmcnt(0)" ::: "memory");
    }
    __builtin_amdgcn_s_barrier();
    __builtin_amdgcn_sched_barrier(0);

    bf16x8 a[4];
#pragma unroll
    for (int mf = 0; mf < 4; ++mf)
      a[mf] = *(const bf16x8*)&Als[cur][((w >> 1) * 4 + mf) * 512 + l * 8];
#pragma unroll
    for (int mf = 0; mf < 4; ++mf)
#pragma unroll
      for (int nf = 0; nf < 2; ++nf)
        acc[mf][nf] = __builtin_amdgcn_mfma_f32_16x16x32_bf16(a[mf], bc[nf],
                                                              acc[mf][nf], 0, 0, 0);
    __builtin_amdgcn_s_barrier();
  };

  for (int kt2 = 0; kt2 < 32; kt2 += 2) {
    step(kt2, breg[0], breg[1]);
    step(kt2 + 1, breg[1], breg[0]);
  }

#pragma unroll
  for (int nf = 0; nf < 2; ++nf) {
    const int n = nbase + wc + nf * 16 + lo;
    const float bsv = b0[n];
#pragma unroll
    for (int mf = 0; mf < 4; ++mf)
#pragma unroll
      for (int r = 0; r < 4; ++r) {
        const int m = mbase + wr + mf * 16 + hi * 4 + r;
        outF[(size_t)m * 1024 + n] = acc[mf][nf][r] + bsv;
      }
  }
}

// -------- flash attention: QUAD q-tiles + XCD-resident KV (r15 structure,
// barrier-free, reg-direct packed K/V) + T5 setprio around MFMA clusters
// (independent-wave regime -> m191-positive).
#define PSTR 36
__global__ __launch_bounds__(512, 2) void kAttn(const u16* __restrict__ Qp,
                                                const u16* __restrict__ Kp,
                                                const u16* __restrict__ Vp,
                                                u16* __restrict__ AOp) {
  __shared__ __align__(16) u16 Pl[8][16 * PSTR];     // per-wave P (9 KB)
  __shared__ __align__(16) float Red[4][2][16][64];  // odd-half O partials
  __shared__ float RedL[4][2][64];                   // odd-half denom partials
  const int tid = threadIdx.x, l = tid & 63, w = tid >> 6;  // w in [0,8)
  const int grp = w >> 1, half = w & 1;
  const int g = l >> 4, c = l & 15;
  const int id = blockIdx.x;  // 256 blocks
  const int xcd = id & 7, rem = id >> 3;
  const int pi = rem & 7, bh = (rem >> 3) * 8 + xcd;  // bh%8 == xcd
  const int qt0 = 31 - pi, qt1 = 16 + pi, qt2 = 15 - pi, qt3 = pi;
  const size_t head = (size_t)bh * 131072;
  const u16* Kh = Kp + head;
  const u16* Vh = Vp + head;

  bf16x8 aq0[2], aq1[2], aq2[2], aq3[2];
#pragma unroll
  for (int ks = 0; ks < 2; ++ks) {
    aq0[ks] = *(const bf16x8*)&Qp[head + (size_t)((qt0 * 4 + grp) * 2 + ks) * 512 + l * 8];
    aq1[ks] = *(const bf16x8*)&Qp[head + (size_t)((qt1 * 4 + grp) * 2 + ks) * 512 + l * 8];
    aq2[ks] = *(const bf16x8*)&Qp[head + (size_t)((qt2 * 4 + grp) * 2 + ks) * 512 + l * 8];
    aq3[ks] = *(const bf16x8*)&Qp[head + (size_t)((qt3 * 4 + grp) * 2 + ks) * 512 + l * 8];
  }

  f32x4 acc0[4], acc1[4], acc2[4], acc3[4];
#pragma unroll
  for (int i = 0; i < 4; ++i) {
    acc0[i] = (f32x4){0.f, 0.f, 0.f, 0.f};
    acc1[i] = (f32x4){0.f, 0.f, 0.f, 0.f};
    acc2[i] = (f32x4){0.f, 0.f, 0.f, 0.f};
    acc3[i] = (f32x4){0.f, 0.f, 0.f, 0.f};
  }
  float l0 = 0.f, l1 = 0.f, l2 = 0.f, l3 = 0.f;

  bf16x8 kr[4];  // [sf*2+ks]
#pragma unroll
  for (int f = 0; f < 4; ++f)
    kr[f] = *(const bf16x8*)&Kh[(size_t)((half * 2 + (f >> 1)) * 2 + (f & 1)) * 512 + l * 8];
  bf16x8 vr[4];

  auto qkTile = [&](const bf16x8* aq, f32x4* sT) {
    __builtin_amdgcn_s_setprio(1);
#pragma unroll
    for (int sf = 0; sf < 2; ++sf)
#pragma unroll
      for (int ks = 0; ks < 2; ++ks)
        sT[sf] = __builtin_amdgcn_mfma_f32_16x16x32_bf16(kr[sf * 2 + ks], aq[ks],
                                                         sT[sf], 0, 0, 0);
    __builtin_amdgcn_s_setprio(0);
  };

  auto finishTile = [&](const f32x4* sT, bool diag, f32x4* accO, float& lpart) {
    float v[8];
#pragma unroll
    for (int sf = 0; sf < 2; ++sf)
#pragma unroll
      for (int r = 0; r < 4; ++r) v[sf * 4 + r] = sT[sf][r];
    if (diag) {
      const int qin = grp * 16 + c;
#pragma unroll
      for (int sf = 0; sf < 2; ++sf)
#pragma unroll
        for (int r = 0; r < 4; ++r)
          if (half * 32 + sf * 16 + g * 4 + r > qin) v[sf * 4 + r] = -__builtin_inff();
    }
    float p[8];
#pragma unroll
    for (int i = 0; i < 8; ++i) p[i] = __builtin_exp2f(v[i]);  // exp2(-inf)=0
#pragma unroll
    for (int sf = 0; sf < 2; ++sf) {
      u16x4 q4 = {f2bf(p[sf * 4 + 0]), f2bf(p[sf * 4 + 1]),
                  f2bf(p[sf * 4 + 2]), f2bf(p[sf * 4 + 3])};
      *(u16x4*)&Pl[w][c * PSTR + sf * 16 + g * 4] = q4;
    }
    lpart += ((p[0] + p[1]) + (p[2] + p[3])) + ((p[4] + p[5]) + (p[6] + p[7]));
    bf16x8 pf = *(const bf16x8*)&Pl[w][c * PSTR + g * 8];
    __builtin_amdgcn_s_setprio(1);
#pragma unroll
    for (int nd = 0; nd < 4; ++nd)
      accO[nd] = __builtin_amdgcn_mfma_f32_16x16x32_bf16(pf, vr[nd], accO[nd], 0, 0, 0);
    __builtin_amdgcn_s_setprio(0);
  };

  const int nst = qt0 + 1;
  for (int st = 0; st < nst; ++st) {
#pragma unroll
    for (int nd = 0; nd < 4; ++nd)
      vr[nd] = *(const bf16x8*)&Vh[(size_t)(nd * 64 + st * 2 + half) * 512 + l * 8];

    f32x4 sT[2];
    if (st <= qt3) {
#pragma unroll
      for (int i = 0; i < 2; ++i) sT[i] = (f32x4){0.f, 0.f, 0.f, 0.f};
      qkTile(aq3, sT);
      finishTile(sT, st == qt3, acc3, l3);
    }
    if (st <= qt2) {
#pragma unroll
      for (int i = 0; i < 2; ++i) sT[i] = (f32x4){0.f, 0.f, 0.f, 0.f};
      qkTile(aq2, sT);
      finishTile(sT, st == qt2, acc2, l2);
    }
    if (st <= qt1) {
#pragma unroll
      for (int i = 0; i < 2; ++i) sT[i] = (f32x4){0.f, 0.f, 0.f, 0.f};
      qkTile(aq1, sT);
      finishTile(sT, st == qt1, acc1, l1);
    }
    {
#pragma unroll
      for (int i = 0; i < 2; ++i) sT[i] = (f32x4){0.f, 0.f, 0.f, 0.f};
      qkTile(aq0, sT);
      if (st < qt0) {
#pragma unroll
        for (int f = 0; f < 4; ++f)
          kr[f] = *(const bf16x8*)&Kh[(size_t)(((st + 1) * 4 + half * 2 + (f >> 1)) * 2 +
                                               (f & 1)) * 512 + l * 8];
      }
      finishTile(sT, st == qt0, acc0, l0);
    }
  }

  const int b = bh >> 4, h = bh & 15;
  auto writeOut = [&](int qt, const f32x4* accO, float lc) {
#pragma unroll
    for (int r = 0; r < 4; ++r) {
      const float lr = __shfl(lc, g * 4 + r);
      const float rin = 1.0f / lr;
      const int mg = b * 2048 + qt * 64 + grp * 16 + g * 4 + r;
#pragma unroll
      for (int nd = 0; nd < 4; ++nd) {
        const int col = h * 64 + nd * 16 + c;
        AOp[paddr(mg, col, 32)] = f2bf(accO[nd][r] * rin);  // packed for GEMM-O
      }
    }
  };
  auto combinePair = [&](f32x4* accX, float lX, int qtX, f32x4* accY, float lY,
                         int qtY) {
    float lcX = lX + __shfl_xor(lX, 16);
    lcX += __shfl_xor(lcX, 32);
    float lcY = lY + __shfl_xor(lY, 16);
    lcY += __shfl_xor(lcY, 32);
    __syncthreads();
    if (half) {
#pragma unroll
      for (int nd = 0; nd < 4; ++nd)
#pragma unroll
        for (int r = 0; r < 4; ++r) {
          Red[grp][0][nd * 4 + r][l] = accX[nd][r];
          Red[grp][1][nd * 4 + r][l] = accY[nd][r];
        }
      RedL[grp][0][l] = lcX;
      RedL[grp][1][l] = lcY;
    }
    __syncthreads();
    if (!half) {
#pragma unroll
      for (int nd = 0; nd < 4; ++nd)
#pragma unroll
        for (int r = 0; r < 4; ++r) {
          accX[nd][r] += Red[grp][0][nd * 4 + r][l];
          accY[nd][r] += Red[grp][1][nd * 4 + r][l];
        }
      writeOut(qtX, accX, lcX + RedL[grp][0][l]);
      writeOut(qtY, accY, lcY + RedL[grp][1][l]);
    }
  };
  combinePair(acc0, l0, qt0, acc1, l1, qt1);
  combinePair(acc2, l2, qt2, acc3, l3, qt3);
}

extern "C" void kernel_launch(void* const* d_in, const int* in_sizes, int n_in,
                              void* d_out, int out_size, void* d_ws, size_t ws_size,
                              hipStream_t stream) {
  const float* src = (const float*)d_in[0];
  const float* Wq = (const float*)d_in[2];
  const float* bq = (const float*)d_in[3];
  const float* Wk = (const float*)d_in[4];
  const float* bk = (const float*)d_in[5];
  const float* Wv = (const float*)d_in[6];
  const float* bv = (const float*)d_in[7];
  const float* Wo = (const float*)d_in[8];
  const float* bo = (const float*)d_in[9];
  float* out = (float*)d_out;

  char* ws = (char*)d_ws;
  u16* Wp = (u16*)(ws);                           // [4][1024][1024] bf16 packed
  u16* Xp = (u16*)(ws + 8ull * 1024 * 1024);      // [4096][1024] bf16 packed
  u16* Qb = (u16*)(ws + 16ull * 1024 * 1024);     // Qp,Kp,Vp packed
  u16* AOp = (u16*)(ws + 40ull * 1024 * 1024);    // [4096][1024] bf16 packed

  kPrep<<<dim3(8192), dim3(256), 0, stream>>>(src, Xp, Wq, Wk, Wv, Wo, Wp);
  kGemmQKV<<<dim3(768), dim3(256), 0, stream>>>(Xp, Wp, bq, bk, bv, Qb);
  kAttn<<<dim3(256), dim3(512), 0, stream>>>(Qb, Qb + 4 * 1048576,
                                             Qb + 8 * 1048576, AOp);
  kGemmO<<<dim3(512), dim3(256), 0, stream>>>(AOp, Wp + 3ull * 1048576, bo, out);
}